// Round 3
// baseline (333.289 us; speedup 1.0000x reference)
//
#include <hip/hip_runtime.h>
#include <math.h>

constexpr int Bn = 64, Lc = 1024, Lq = 128, Dd = 128;

typedef __attribute__((ext_vector_type(8))) short short8_t;  // 8 bf16
typedef __attribute__((ext_vector_type(4))) short short4_t;  // 4 bf16
typedef __attribute__((ext_vector_type(4))) float f32x4;

__device__ __forceinline__ short f2bf(float x) {
    unsigned u = __float_as_uint(x);
    u += 0x7FFFu + ((u >> 16) & 1u);   // round-to-nearest-even
    return (short)(u >> 16);
}

constexpr int AS = 132;   // [row][d] LDS stride (shorts): 2-bank lane advance, uniform banks
constexpr int TS = 70;    // transpose buf stride
constexpr int CS = 68;    // k2 staging stride

// ================== k1_fused: prep + scores + exp + sums ==================
// grid (Lc/64, B), 256 thr. Writes E16 [b,i,j], ET16 [b,j,i], CT16 [b,d,i],
// QT16 [b,d,j] (block x==0 only), colsum (atomic), rowsumInv.
__global__ __launch_bounds__(256) void k1_fused(
    const float* __restrict__ C, const float* __restrict__ Q,
    const int* __restrict__ Cmask, const int* __restrict__ Qmask,
    const float* __restrict__ w_c, const float* __restrict__ w_q,
    const float* __restrict__ w_mul, const float* __restrict__ bias,
    short* __restrict__ E16, short* __restrict__ ET16,
    short* __restrict__ CT16, short* __restrict__ QT16,
    float* __restrict__ colsum, float* __restrict__ rowsumInv)
{
    __shared__ short Abuf[64 * AS];    // C*w_mul bf16, [i][d]
    __shared__ short Bbuf[128 * AS];   // Q bf16, [j][d]; first 128*TS doubles as Tbuf
    __shared__ float s0L[64], cmL[64], s1L[128], qmL[128];
    short* Tbuf = Bbuf;                // cm*C transposed [d][i], phases 1-2 only

    int b = blockIdx.y, i0 = blockIdx.x * 64, tid = threadIdx.x;

    // ---- phase 1: C tile -> Abuf (cw), Tbuf (cm*C, [d][i]), s0, cm ----
    const float4* C4 = (const float4*)(C + ((size_t)(b * Lc + i0)) * Dd);
    #pragma unroll
    for (int k = 0; k < 8; ++k) {
        int idx = tid + k * 256;           // 2048 float4 = 64 i x 32 d4
        int i = idx >> 5, d4 = idx & 31;
        float4 v = C4[idx];
        float4 wm = ((const float4*)w_mul)[d4];
        short4_t cw; cw[0]=f2bf(v.x*wm.x); cw[1]=f2bf(v.y*wm.y); cw[2]=f2bf(v.z*wm.z); cw[3]=f2bf(v.w*wm.w);
        *(short4_t*)&Abuf[i * AS + d4 * 4] = cw;
        float cm = (Cmask[b * Lc + i0 + i] != 0) ? 1.0f : 0.0f;
        Tbuf[(d4*4+0)*TS + i] = f2bf(cm * v.x);
        Tbuf[(d4*4+1)*TS + i] = f2bf(cm * v.y);
        Tbuf[(d4*4+2)*TS + i] = f2bf(cm * v.z);
        Tbuf[(d4*4+3)*TS + i] = f2bf(cm * v.w);
        float4 wc = ((const float4*)w_c)[d4];
        float dot = v.x*wc.x + v.y*wc.y + v.z*wc.z + v.w*wc.w;
        #pragma unroll
        for (int off = 1; off < 32; off <<= 1) dot += __shfl_xor(dot, off, 64);
        if ((tid & 31) == 0) { s0L[i] = dot; cmL[i] = cm; }
    }
    __syncthreads();

    // ---- phase 2: CT16 out (coalesced) ----
    #pragma unroll
    for (int k = 0; k < 8; ++k) {
        int idx = tid + k * 256;           // 2048 short4 = 128 d x 16 i4
        int d = idx >> 4, i4 = idx & 15;
        *(short4_t*)&CT16[((size_t)(b * Dd + d)) * Lc + i0 + i4 * 4] =
            *(short4_t*)&Tbuf[d * TS + i4 * 4];
    }
    __syncthreads();

    // ---- phase 3: Q -> Bbuf (overwrites Tbuf region), s1, qm ----
    const float4* Q4 = (const float4*)(Q + (size_t)b * Lq * Dd);
    #pragma unroll
    for (int k = 0; k < 16; ++k) {
        int idx = tid + k * 256;           // 4096 float4 = 128 j x 32 d4
        int j = idx >> 5, d4 = idx & 31;
        float4 v = Q4[idx];
        short4_t qv; qv[0]=f2bf(v.x); qv[1]=f2bf(v.y); qv[2]=f2bf(v.z); qv[3]=f2bf(v.w);
        *(short4_t*)&Bbuf[j * AS + d4 * 4] = qv;
        float4 wq = ((const float4*)w_q)[d4];
        float dot = v.x*wq.x + v.y*wq.y + v.z*wq.z + v.w*wq.w;
        #pragma unroll
        for (int off = 1; off < 32; off <<= 1) dot += __shfl_xor(dot, off, 64);
        if ((tid & 31) == 0) {
            s1L[j] = dot;
            qmL[j] = (Qmask[b * Lq + j] != 0) ? 1.0f : 0.0f;
        }
    }
    __syncthreads();

    // ---- phase 4: MFMA S = Cw @ Q^T ----
    int w = tid >> 6, lane = tid & 63, lm = lane & 15, quad = lane >> 4;
    int iw = i0 + w * 16;
    f32x4 acc[8];
    #pragma unroll
    for (int t = 0; t < 8; ++t) acc[t] = (f32x4){0.f,0.f,0.f,0.f};
    #pragma unroll
    for (int ks = 0; ks < 4; ++ks) {
        short8_t a = *(short8_t*)&Abuf[(w * 16 + lm) * AS + ks * 32 + quad * 8];
        #pragma unroll
        for (int jt = 0; jt < 8; ++jt) {
            short8_t bf = *(short8_t*)&Bbuf[(jt * 16 + lm) * AS + ks * 32 + quad * 8];
            acc[jt] = __builtin_amdgcn_mfma_f32_16x16x32_bf16(a, bf, acc[jt], 0, 0, 0);
        }
    }

    // ---- phase 5: exp + E/ET writes + colsum + rowsumInv ----
    float s0[4], cm[4];
    #pragma unroll
    for (int r = 0; r < 4; ++r) {
        s0[r] = s0L[w * 16 + quad * 4 + r];
        cm[r] = cmL[w * 16 + quad * 4 + r];
    }
    float bb = bias[0];
    float rowpart[4] = {0.f, 0.f, 0.f, 0.f};
    #pragma unroll
    for (int jt = 0; jt < 8; ++jt) {
        int j = jt * 16 + lm;
        float s1 = s1L[j] + bb;
        float qm = qmL[j];
        float cs = 0.f;
        short4_t etp;
        #pragma unroll
        for (int r = 0; r < 4; ++r) {
            float e = __expf(acc[jt][r] + s0[r] + s1);
            short eb = f2bf(e);
            E16[((size_t)(b * Lc + iw + quad * 4 + r)) * Lq + j] = eb;
            etp[r] = eb;
            rowpart[r] += qm * e;
            cs += cm[r] * e;
        }
        *(short4_t*)&ET16[((size_t)(b * Lq + j)) * Lc + iw + quad * 4] = etp;
        cs += __shfl_xor(cs, 16, 64);
        cs += __shfl_xor(cs, 32, 64);
        if (lane < 16) atomicAdd(&colsum[b * Lq + j], cs);
    }
    #pragma unroll
    for (int r = 0; r < 4; ++r) {
        float v = rowpart[r];
        v += __shfl_xor(v, 1, 64); v += __shfl_xor(v, 2, 64);
        v += __shfl_xor(v, 4, 64); v += __shfl_xor(v, 8, 64);
        if (lm == 0) rowsumInv[b * Lc + iw + quad * 4 + r] = 1.0f / v;
    }

    // ---- phase 6: QT16 (qm-folded transpose of Q), one block per batch ----
    if (blockIdx.x == 0) {
        #pragma unroll
        for (int k = 0; k < 16; ++k) {
            int idx = tid + k * 256;       // 4096 short4 = 128 d x 32 j4
            int d = idx >> 5, j4 = idx & 31;
            short4_t o;
            #pragma unroll
            for (int r = 0; r < 4; ++r) {
                int j = j4 * 4 + r;
                o[r] = (qmL[j] != 0.f) ? Bbuf[j * AS + d] : (short)0;
            }
            *(short4_t*)&QT16[((size_t)(b * Dd + d)) * Lq + j4 * 4] = o;
        }
    }
}

// ================== k2_fused: T[j,d] = S2^T @ C, scaled, -> TT16 [b,d,j] ==================
// grid (2, B): block = 64-j half x 128 d, K=1024 loop. No atomics.
__global__ __launch_bounds__(256) void k2_fused(
    const short* __restrict__ ET16, const short* __restrict__ CT16,
    const float* __restrict__ colsum, const int* __restrict__ Qmask,
    short* __restrict__ TT16)
{
    __shared__ short CTs[128 * CS];   // staged CT k-slice; reused for out transpose
    int b = blockIdx.y, jh = blockIdx.x;
    int tid = threadIdx.x, w = tid >> 6, lane = tid & 63;
    int lm = lane & 15, quad = lane >> 4;
    int jw = jh * 64 + w * 16;

    f32x4 acc[8];
    #pragma unroll
    for (int t = 0; t < 8; ++t) acc[t] = (f32x4){0.f,0.f,0.f,0.f};

    for (int ic = 0; ic < 16; ++ic) {
        #pragma unroll
        for (int k = 0; k < 8; ++k) {
            int idx = tid + k * 256;       // 2048 short4 = 128 d x 16 i4
            int d = idx >> 4, i4 = idx & 15;
            *(short4_t*)&CTs[d * CS + i4 * 4] =
                *(const short4_t*)&CT16[((size_t)(b * Dd + d)) * Lc + ic * 64 + i4 * 4];
        }
        __syncthreads();
        #pragma unroll
        for (int ks = 0; ks < 2; ++ks) {
            short8_t a = *(const short8_t*)&ET16[((size_t)(b * Lq + jw + lm)) * Lc + ic * 64 + ks * 32 + quad * 8];
            #pragma unroll
            for (int dt = 0; dt < 8; ++dt) {
                short8_t bf = *(short8_t*)&CTs[(dt * 16 + lm) * CS + ks * 32 + quad * 8];
                acc[dt] = __builtin_amdgcn_mfma_f32_16x16x32_bf16(a, bf, acc[dt], 0, 0, 0);
            }
        }
        __syncthreads();
    }

    // scale rows j by qm/colsum, transpose via LDS, write TT16
    float invq[4];
    #pragma unroll
    for (int r = 0; r < 4; ++r) {
        int j = jw + quad * 4 + r;
        float csv = colsum[b * Lq + j];
        invq[r] = (Qmask[b * Lq + j] != 0) ? (1.0f / csv) : 0.0f;
    }
    #pragma unroll
    for (int dt = 0; dt < 8; ++dt)
        #pragma unroll
        for (int r = 0; r < 4; ++r)
            CTs[(dt * 16 + lm) * CS + (w * 16 + quad * 4 + r)] = f2bf(acc[dt][r] * invq[r]);
    __syncthreads();
    #pragma unroll
    for (int k = 0; k < 8; ++k) {
        int idx = tid + k * 256;           // 2048 short4 = 128 d x 16 j4
        int d = idx >> 4, j4 = idx & 15;
        *(short4_t*)&TT16[((size_t)(b * Dd + d)) * Lq + jh * 64 + j4 * 4] =
            *(short4_t*)&CTs[d * CS + j4 * 4];
    }
}

// ================== k3: A = (E@Qm)*rsInv, Bm = (E@Tm)*rsInv, out ==================
__global__ __launch_bounds__(256) void k3_out(
    const short* __restrict__ E16, const short* __restrict__ QT16,
    const short* __restrict__ TT16, const float* __restrict__ rowsumInv,
    const float* __restrict__ C, float* __restrict__ out)
{
    int b = blockIdx.y, i0 = blockIdx.x * 64;
    int tid = threadIdx.x, w = tid >> 6, lane = tid & 63;
    int lm = lane & 15, quad = lane >> 4;
    int iw = i0 + w * 16;

    f32x4 accQ[8], accT[8];
    #pragma unroll
    for (int t = 0; t < 8; ++t) { accQ[t] = (f32x4){0.f,0.f,0.f,0.f}; accT[t] = (f32x4){0.f,0.f,0.f,0.f}; }

    const short8_t* Arow = (const short8_t*)(E16 + ((size_t)(b * Lc + iw + lm)) * Lq);
    #pragma unroll
    for (int ks = 0; ks < 4; ++ks) {
        short8_t a = Arow[ks * 4 + quad];
        int ko = ks * 32 + quad * 8;
        #pragma unroll
        for (int dt = 0; dt < 8; ++dt) {
            short8_t bq = *(const short8_t*)&QT16[((size_t)(b * Dd + dt * 16 + lm)) * Lq + ko];
            accQ[dt] = __builtin_amdgcn_mfma_f32_16x16x32_bf16(a, bq, accQ[dt], 0, 0, 0);
            short8_t bt = *(const short8_t*)&TT16[((size_t)(b * Dd + dt * 16 + lm)) * Lq + ko];
            accT[dt] = __builtin_amdgcn_mfma_f32_16x16x32_bf16(a, bt, accT[dt], 0, 0, 0);
        }
    }

    float rs[4];
    #pragma unroll
    for (int r = 0; r < 4; ++r) rs[r] = rowsumInv[b * Lc + iw + quad * 4 + r];

    #pragma unroll
    for (int dt = 0; dt < 8; ++dt) {
        int d = dt * 16 + lm;
        #pragma unroll
        for (int r = 0; r < 4; ++r) {
            int i = iw + quad * 4 + r;
            float av = accQ[dt][r] * rs[r];
            float bm = accT[dt][r] * rs[r];
            float cv = C[((size_t)(b * Lc + i)) * Dd + d];
            size_t base = ((size_t)(b * Lc + i)) * (4 * Dd);
            out[base + 0 * Dd + d] = cv;
            out[base + 1 * Dd + d] = av;
            out[base + 2 * Dd + d] = cv * av;
            out[base + 3 * Dd + d] = cv * bm;
        }
    }
}

extern "C" void kernel_launch(void* const* d_in, const int* in_sizes, int n_in,
                              void* d_out, int out_size, void* d_ws, size_t ws_size,
                              hipStream_t stream) {
    const float* C     = (const float*)d_in[0];
    const float* Q     = (const float*)d_in[1];
    const int*   Cmask = (const int*)d_in[2];
    const int*   Qmask = (const int*)d_in[3];
    const float* w_c   = (const float*)d_in[4];
    const float* w_q   = (const float*)d_in[5];
    const float* w_mul = (const float*)d_in[6];
    const float* bias  = (const float*)d_in[7];
    float* out = (float*)d_out;

    char* p = (char*)d_ws;
    const size_t NE = (size_t)Bn * Lc * Lq;
    const size_t ND = (size_t)Bn * Lc * Dd;
    const size_t NQ = (size_t)Bn * Lq * Dd;
    short* E16  = (short*)p; p += NE * 2;
    short* ET16 = (short*)p; p += NE * 2;
    short* CT16 = (short*)p; p += ND * 2;
    short* QT16 = (short*)p; p += NQ * 2;
    short* TT16 = (short*)p; p += NQ * 2;
    float* colsum    = (float*)p; p += (size_t)Bn * Lq * 4;
    float* rowsumInv = (float*)p; p += (size_t)Bn * Lc * 4;

    hipMemsetAsync(colsum, 0, (size_t)Bn * Lq * 4, stream);
    k1_fused<<<dim3(Lc / 64, Bn), 256, 0, stream>>>(C, Q, Cmask, Qmask, w_c, w_q, w_mul, bias,
                                                    E16, ET16, CT16, QT16, colsum, rowsumInv);
    k2_fused<<<dim3(2, Bn), 256, 0, stream>>>(ET16, CT16, colsum, Qmask, TT16);
    k3_out<<<dim3(Lc / 64, Bn), 256, 0, stream>>>(E16, QT16, TT16, rowsumInv, C, out);
}

// Round 4
// 275.790 us; speedup vs baseline: 1.2085x; 1.2085x over previous
//
#include <hip/hip_runtime.h>
#include <math.h>

constexpr int Bn = 64, Lc = 1024, Lq = 128, Dd = 128;

typedef __attribute__((ext_vector_type(8))) short short8_t;  // 8 bf16
typedef __attribute__((ext_vector_type(4))) short short4_t;  // 4 bf16
typedef __attribute__((ext_vector_type(4))) float f32x4;

__device__ __forceinline__ short f2bf(float x) {
    unsigned u = __float_as_uint(x);
    u += 0x7FFFu + ((u >> 16) & 1u);   // round-to-nearest-even
    return (short)(u >> 16);
}

constexpr int AS = 132;   // [row][d] LDS stride (shorts)
constexpr int TS = 70;    // k1 transpose buf stride
constexpr int CS = 68;    // k2 staging stride (shorts)
constexpr int QS = 36;    // k2 out-transpose stride (shorts)

// ================== k1_fused: prep + scores + exp + sums ==================
__global__ __launch_bounds__(256) void k1_fused(
    const float* __restrict__ C, const float* __restrict__ Q,
    const int* __restrict__ Cmask, const int* __restrict__ Qmask,
    const float* __restrict__ w_c, const float* __restrict__ w_q,
    const float* __restrict__ w_mul, const float* __restrict__ bias,
    short* __restrict__ E16, short* __restrict__ ET16,
    short* __restrict__ CT16, short* __restrict__ QT16,
    float* __restrict__ colsum, float* __restrict__ rowsumInv)
{
    __shared__ short Abuf[64 * AS];    // C*w_mul bf16, [i][d]
    __shared__ short Bbuf[128 * AS];   // Q bf16, [j][d]; first 128*TS doubles as Tbuf
    __shared__ float s0L[64], cmL[64], s1L[128], qmL[128];
    short* Tbuf = Bbuf;

    int b = blockIdx.y, i0 = blockIdx.x * 64, tid = threadIdx.x;

    // ---- phase 1: C tile -> Abuf (cw), Tbuf (cm*C, [d][i]), s0, cm ----
    const float4* C4 = (const float4*)(C + ((size_t)(b * Lc + i0)) * Dd);
    #pragma unroll
    for (int k = 0; k < 8; ++k) {
        int idx = tid + k * 256;
        int i = idx >> 5, d4 = idx & 31;
        float4 v = C4[idx];
        float4 wm = ((const float4*)w_mul)[d4];
        short4_t cw; cw[0]=f2bf(v.x*wm.x); cw[1]=f2bf(v.y*wm.y); cw[2]=f2bf(v.z*wm.z); cw[3]=f2bf(v.w*wm.w);
        *(short4_t*)&Abuf[i * AS + d4 * 4] = cw;
        float cm = (Cmask[b * Lc + i0 + i] != 0) ? 1.0f : 0.0f;
        Tbuf[(d4*4+0)*TS + i] = f2bf(cm * v.x);
        Tbuf[(d4*4+1)*TS + i] = f2bf(cm * v.y);
        Tbuf[(d4*4+2)*TS + i] = f2bf(cm * v.z);
        Tbuf[(d4*4+3)*TS + i] = f2bf(cm * v.w);
        float4 wc = ((const float4*)w_c)[d4];
        float dot = v.x*wc.x + v.y*wc.y + v.z*wc.z + v.w*wc.w;
        #pragma unroll
        for (int off = 1; off < 32; off <<= 1) dot += __shfl_xor(dot, off, 64);
        if ((tid & 31) == 0) { s0L[i] = dot; cmL[i] = cm; }
    }
    __syncthreads();

    // ---- phase 2: CT16 out ----
    #pragma unroll
    for (int k = 0; k < 8; ++k) {
        int idx = tid + k * 256;
        int d = idx >> 4, i4 = idx & 15;
        *(short4_t*)&CT16[((size_t)(b * Dd + d)) * Lc + i0 + i4 * 4] =
            *(short4_t*)&Tbuf[d * TS + i4 * 4];
    }
    __syncthreads();

    // ---- phase 3: Q -> Bbuf, s1, qm ----
    const float4* Q4 = (const float4*)(Q + (size_t)b * Lq * Dd);
    #pragma unroll
    for (int k = 0; k < 16; ++k) {
        int idx = tid + k * 256;
        int j = idx >> 5, d4 = idx & 31;
        float4 v = Q4[idx];
        short4_t qv; qv[0]=f2bf(v.x); qv[1]=f2bf(v.y); qv[2]=f2bf(v.z); qv[3]=f2bf(v.w);
        *(short4_t*)&Bbuf[j * AS + d4 * 4] = qv;
        float4 wq = ((const float4*)w_q)[d4];
        float dot = v.x*wq.x + v.y*wq.y + v.z*wq.z + v.w*wq.w;
        #pragma unroll
        for (int off = 1; off < 32; off <<= 1) dot += __shfl_xor(dot, off, 64);
        if ((tid & 31) == 0) {
            s1L[j] = dot;
            qmL[j] = (Qmask[b * Lq + j] != 0) ? 1.0f : 0.0f;
        }
    }
    __syncthreads();

    // ---- phase 4: MFMA S = Cw @ Q^T ----
    int w = tid >> 6, lane = tid & 63, lm = lane & 15, quad = lane >> 4;
    int iw = i0 + w * 16;
    f32x4 acc[8];
    #pragma unroll
    for (int t = 0; t < 8; ++t) acc[t] = (f32x4){0.f,0.f,0.f,0.f};
    #pragma unroll
    for (int ks = 0; ks < 4; ++ks) {
        short8_t a = *(short8_t*)&Abuf[(w * 16 + lm) * AS + ks * 32 + quad * 8];
        #pragma unroll
        for (int jt = 0; jt < 8; ++jt) {
            short8_t bf = *(short8_t*)&Bbuf[(jt * 16 + lm) * AS + ks * 32 + quad * 8];
            acc[jt] = __builtin_amdgcn_mfma_f32_16x16x32_bf16(a, bf, acc[jt], 0, 0, 0);
        }
    }

    // ---- phase 5: exp + E/ET writes + colsum + rowsumInv ----
    float s0[4], cm[4];
    #pragma unroll
    for (int r = 0; r < 4; ++r) {
        s0[r] = s0L[w * 16 + quad * 4 + r];
        cm[r] = cmL[w * 16 + quad * 4 + r];
    }
    float bb = bias[0];
    float rowpart[4] = {0.f, 0.f, 0.f, 0.f};
    #pragma unroll
    for (int jt = 0; jt < 8; ++jt) {
        int j = jt * 16 + lm;
        float s1 = s1L[j] + bb;
        float qm = qmL[j];
        float cs = 0.f;
        short4_t etp;
        #pragma unroll
        for (int r = 0; r < 4; ++r) {
            float e = __expf(acc[jt][r] + s0[r] + s1);
            short eb = f2bf(e);
            E16[((size_t)(b * Lc + iw + quad * 4 + r)) * Lq + j] = eb;
            etp[r] = eb;
            rowpart[r] += qm * e;
            cs += cm[r] * e;
        }
        *(short4_t*)&ET16[((size_t)(b * Lq + j)) * Lc + iw + quad * 4] = etp;
        cs += __shfl_xor(cs, 16, 64);
        cs += __shfl_xor(cs, 32, 64);
        if (lane < 16) atomicAdd(&colsum[b * Lq + j], cs);
    }
    #pragma unroll
    for (int r = 0; r < 4; ++r) {
        float v = rowpart[r];
        v += __shfl_xor(v, 1, 64); v += __shfl_xor(v, 2, 64);
        v += __shfl_xor(v, 4, 64); v += __shfl_xor(v, 8, 64);
        if (lm == 0) rowsumInv[b * Lc + iw + quad * 4 + r] = 1.0f / v;
    }

    // ---- phase 6: QT16 ----
    if (blockIdx.x == 0) {
        #pragma unroll
        for (int k = 0; k < 16; ++k) {
            int idx = tid + k * 256;
            int d = idx >> 5, j4 = idx & 31;
            short4_t o;
            #pragma unroll
            for (int r = 0; r < 4; ++r) {
                int j = j4 * 4 + r;
                o[r] = (qmL[j] != 0.f) ? Bbuf[j * AS + d] : (short)0;
            }
            *(short4_t*)&QT16[((size_t)(b * Dd + d)) * Lq + j4 * 4] = o;
        }
    }
}

// ================== k2_fused: T = S2^T @ C -> TT16 [b,d,j]; grid (4,B) ==================
__global__ __launch_bounds__(256) void k2_fused(
    const short* __restrict__ ET16, const short* __restrict__ CT16,
    const float* __restrict__ colsum, const int* __restrict__ Qmask,
    short* __restrict__ TT16)
{
    __shared__ short CTs[128 * CS];   // staged CT k-slice; reused for out transpose
    int b = blockIdx.y, jq = blockIdx.x;
    int tid = threadIdx.x, w = tid >> 6, lane = tid & 63;
    int lm = lane & 15, quad = lane >> 4;
    int dq = w >> 1;                       // d-half: 0 -> d 0..63, 1 -> 64..127
    int jw = jq * 32 + (w & 1) * 16;       // 16-j subtile

    f32x4 acc[4];
    #pragma unroll
    for (int t = 0; t < 4; ++t) acc[t] = (f32x4){0.f,0.f,0.f,0.f};

    for (int ic = 0; ic < 16; ++ic) {
        #pragma unroll
        for (int k = 0; k < 8; ++k) {
            int idx = tid + k * 256;       // 2048 short4 = 128 d x 16 i4
            int d = idx >> 4, i4 = idx & 15;
            *(short4_t*)&CTs[d * CS + i4 * 4] =
                *(const short4_t*)&CT16[((size_t)(b * Dd + d)) * Lc + ic * 64 + i4 * 4];
        }
        __syncthreads();
        #pragma unroll
        for (int ks = 0; ks < 2; ++ks) {
            short8_t a = *(const short8_t*)&ET16[((size_t)(b * Lq + jw + lm)) * Lc + ic * 64 + ks * 32 + quad * 8];
            #pragma unroll
            for (int t = 0; t < 4; ++t) {
                int dt = dq * 4 + t;
                short8_t bf = *(short8_t*)&CTs[(dt * 16 + lm) * CS + ks * 32 + quad * 8];
                acc[t] = __builtin_amdgcn_mfma_f32_16x16x32_bf16(a, bf, acc[t], 0, 0, 0);
            }
        }
        __syncthreads();
    }

    float invq[4];
    #pragma unroll
    for (int r = 0; r < 4; ++r) {
        int j = jw + quad * 4 + r;
        float csv = colsum[b * Lq + j];
        invq[r] = (Qmask[b * Lq + j] != 0) ? (1.0f / csv) : 0.0f;
    }
    // transpose via LDS: Tb[d][jl], jl in 0..31
    short* Tb = CTs;
    #pragma unroll
    for (int t = 0; t < 4; ++t) {
        int d = dq * 64 + t * 16 + lm;
        #pragma unroll
        for (int r = 0; r < 4; ++r)
            Tb[d * QS + (w & 1) * 16 + quad * 4 + r] = f2bf(acc[t][r] * invq[r]);
    }
    __syncthreads();
    #pragma unroll
    for (int k = 0; k < 4; ++k) {
        int idx = tid + k * 256;           // 1024 short4 = 128 d x 8 j4
        int d = idx >> 3, j4 = idx & 7;
        *(short4_t*)&TT16[((size_t)(b * Dd + d)) * Lq + jq * 32 + j4 * 4] =
            *(short4_t*)&Tb[d * QS + j4 * 4];
    }
}

// ================== k3: A=(E@Qm)*rs, Bm=(E@Tm)*rs, out=[C,A,C*A,C*Bm] ==================
// LDS-staged B operands + f32 LDS epilogue with float4 stores. grid (16, B).
__global__ __launch_bounds__(256) void k3_out(
    const short* __restrict__ E16, const short* __restrict__ QT16,
    const short* __restrict__ TT16, const float* __restrict__ rowsumInv,
    const float* __restrict__ C, float* __restrict__ out)
{
    __shared__ short Bs[2 * 128 * AS];     // QTs = Bs, TTs = Bs + 128*AS; 67.6 KB
    short* QTs = Bs;
    short* TTs = Bs + 128 * AS;
    float* Af32 = (float*)Bs;              // epilogue overlay: 64*AS f32 = 33.8 KB

    int b = blockIdx.y, i0 = blockIdx.x * 64;
    int tid = threadIdx.x, w = tid >> 6, lane = tid & 63;
    int lm = lane & 15, quad = lane >> 4;
    int iw = i0 + w * 16;

    // ---- stage QT + TT into LDS (short8 coalesced) ----
    {
        const short8_t* QTg = (const short8_t*)(QT16 + (size_t)b * Dd * Lq);
        const short8_t* TTg = (const short8_t*)(TT16 + (size_t)b * Dd * Lq);
        #pragma unroll
        for (int k = 0; k < 8; ++k) {
            int idx = tid + k * 256;       // 2048 short8 = 128 d x 16 j8
            int d = idx >> 4, j8 = idx & 15;
            *(short8_t*)&QTs[d * AS + j8 * 8] = QTg[idx];
            *(short8_t*)&TTs[d * AS + j8 * 8] = TTg[idx];
        }
    }

    // ---- prefetch A fragments (global) + rs while staging lands ----
    short8_t a[4];
    const short8_t* Arow = (const short8_t*)(E16 + ((size_t)(b * Lc + iw + lm)) * Lq);
    #pragma unroll
    for (int ks = 0; ks < 4; ++ks) a[ks] = Arow[ks * 4 + quad];
    float rs[4];
    #pragma unroll
    for (int r = 0; r < 4; ++r) rs[r] = rowsumInv[b * Lc + iw + quad * 4 + r];
    __syncthreads();

    // ---- MFMA from LDS ----
    f32x4 accQ[8], accT[8];
    #pragma unroll
    for (int t = 0; t < 8; ++t) { accQ[t] = (f32x4){0.f,0.f,0.f,0.f}; accT[t] = (f32x4){0.f,0.f,0.f,0.f}; }
    #pragma unroll
    for (int ks = 0; ks < 4; ++ks) {
        int ko = ks * 32 + quad * 8;
        #pragma unroll
        for (int dt = 0; dt < 8; ++dt) {
            short8_t bq = *(short8_t*)&QTs[(dt * 16 + lm) * AS + ko];
            accQ[dt] = __builtin_amdgcn_mfma_f32_16x16x32_bf16(a[ks], bq, accQ[dt], 0, 0, 0);
            short8_t bt = *(short8_t*)&TTs[(dt * 16 + lm) * AS + ko];
            accT[dt] = __builtin_amdgcn_mfma_f32_16x16x32_bf16(a[ks], bt, accT[dt], 0, 0, 0);
        }
    }
    __syncthreads();

    // ---- epilogue phase A: A -> LDS f32, then float4 stores of C, A, C*A ----
    #pragma unroll
    for (int dt = 0; dt < 8; ++dt)
        #pragma unroll
        for (int r = 0; r < 4; ++r)
            Af32[(w * 16 + quad * 4 + r) * AS + dt * 16 + lm] = accQ[dt][r] * rs[r];
    __syncthreads();

    const float4* C4 = (const float4*)(C + ((size_t)(b * Lc + i0)) * Dd);
    float4 cv[8];
    #pragma unroll
    for (int k = 0; k < 8; ++k) {
        int idx = tid + k * 256;           // 2048 float4 = 64 i x 32 d4
        int i = idx >> 5, d4 = idx & 31;
        float4 av = *(float4*)&Af32[i * AS + d4 * 4];
        float4 c = C4[idx];
        cv[k] = c;
        size_t base = ((size_t)(b * Lc + i0 + i)) * (4 * Dd) + d4 * 4;
        *(float4*)&out[base]           = c;
        *(float4*)&out[base + Dd]      = av;
        float4 ca; ca.x = c.x*av.x; ca.y = c.y*av.y; ca.z = c.z*av.z; ca.w = c.w*av.w;
        *(float4*)&out[base + 2 * Dd]  = ca;
    }
    __syncthreads();

    // ---- epilogue phase B: Bm -> LDS f32, then float4 stores of C*Bm ----
    #pragma unroll
    for (int dt = 0; dt < 8; ++dt)
        #pragma unroll
        for (int r = 0; r < 4; ++r)
            Af32[(w * 16 + quad * 4 + r) * AS + dt * 16 + lm] = accT[dt][r] * rs[r];
    __syncthreads();

    #pragma unroll
    for (int k = 0; k < 8; ++k) {
        int idx = tid + k * 256;
        int i = idx >> 5, d4 = idx & 31;
        float4 bm = *(float4*)&Af32[i * AS + d4 * 4];
        float4 c = cv[k];
        size_t base = ((size_t)(b * Lc + i0 + i)) * (4 * Dd) + d4 * 4;
        float4 cb; cb.x = c.x*bm.x; cb.y = c.y*bm.y; cb.z = c.z*bm.z; cb.w = c.w*bm.w;
        *(float4*)&out[base + 3 * Dd]  = cb;
    }
}

extern "C" void kernel_launch(void* const* d_in, const int* in_sizes, int n_in,
                              void* d_out, int out_size, void* d_ws, size_t ws_size,
                              hipStream_t stream) {
    const float* C     = (const float*)d_in[0];
    const float* Q     = (const float*)d_in[1];
    const int*   Cmask = (const int*)d_in[2];
    const int*   Qmask = (const int*)d_in[3];
    const float* w_c   = (const float*)d_in[4];
    const float* w_q   = (const float*)d_in[5];
    const float* w_mul = (const float*)d_in[6];
    const float* bias  = (const float*)d_in[7];
    float* out = (float*)d_out;

    char* p = (char*)d_ws;
    const size_t NE = (size_t)Bn * Lc * Lq;
    const size_t ND = (size_t)Bn * Lc * Dd;
    const size_t NQ = (size_t)Bn * Lq * Dd;
    short* E16  = (short*)p; p += NE * 2;
    short* ET16 = (short*)p; p += NE * 2;
    short* CT16 = (short*)p; p += ND * 2;
    short* QT16 = (short*)p; p += NQ * 2;
    short* TT16 = (short*)p; p += NQ * 2;
    float* colsum    = (float*)p; p += (size_t)Bn * Lq * 4;
    float* rowsumInv = (float*)p; p += (size_t)Bn * Lc * 4;

    hipMemsetAsync(colsum, 0, (size_t)Bn * Lq * 4, stream);
    k1_fused<<<dim3(Lc / 64, Bn), 256, 0, stream>>>(C, Q, Cmask, Qmask, w_c, w_q, w_mul, bias,
                                                    E16, ET16, CT16, QT16, colsum, rowsumInv);
    k2_fused<<<dim3(4, Bn), 256, 0, stream>>>(ET16, CT16, colsum, Qmask, TT16);
    k3_out<<<dim3(Lc / 64, Bn), 256, 0, stream>>>(E16, QT16, TT16, rowsumInv, C, out);
}